// Round 10
// baseline (142.394 us; speedup 1.0000x reference)
//
#include <hip/hip_runtime.h>
#include <math.h>

// Problem constants (B,C,H,W = 8,256,64,64; N = H*W = 4096)
#define BQ 8
#define CQ 256
#define NQ 4096
#define MT 128            // m-tile per block -> 256 blocks, 1/CU
#define NCH 128           // chunks of 32n

typedef short s16x8 __attribute__((ext_vector_type(8)));
typedef short s16x4 __attribute__((ext_vector_type(4)));
typedef float f32x4 __attribute__((ext_vector_type(4)));
typedef unsigned int uint;

static __device__ __forceinline__ float4 ld4(const float* p) { return *(const float4*)p; }

static constexpr float LOG2E = 1.4426950408889634f;

static __device__ __forceinline__ short f2bf(float f) {
    return __builtin_bit_cast(short, (__bf16)f);
}
// monotonic uint key for float compare via atomicMax/Min
static __device__ __forceinline__ uint fkey(float f) {
    uint b = __builtin_bit_cast(uint, f);
    return b ^ (0x80000000u | (uint)((int)b >> 31));
}
static __device__ __forceinline__ float fdec(uint u) {
    uint b = (u & 0x80000000u) ? (u ^ 0x80000000u) : ~u;
    return __builtin_bit_cast(float, b);
}

// -------- K1: f' = (wq.x)*log2e, g = wk.x, xbf = bf16(x), fused batch max/min --------
__global__ void k_fg(const float* __restrict__ x, const float* __restrict__ wq,
                     const float* __restrict__ wk, float* __restrict__ fs,
                     float* __restrict__ g, short* __restrict__ xbf,
                     uint* __restrict__ fmxu, uint* __restrict__ fmnu) {
    int b = blockIdx.y;
    int t = threadIdx.x;
    int nl = (t & 31) * 2;
    int cg = t >> 5;                     // 0..7
    int n = blockIdx.x * 64 + nl;
    const float* xb = x + (size_t)b * CQ * NQ + n;
    uint* xo = (uint*)(xbf + (size_t)b * CQ * NQ + n);
    float f0 = 0.f, f1 = 0.f, g0 = 0.f, g1 = 0.f;
    int c0 = cg * 32;
#pragma unroll 8
    for (int c = c0; c < c0 + 32; ++c) {
        float2 v = *(const float2*)&xb[(size_t)c * NQ];
        f0 = fmaf(wq[c], v.x, f0);
        f1 = fmaf(wq[c], v.y, f1);
        g0 = fmaf(wk[c], v.x, g0);
        g1 = fmaf(wk[c], v.y, g1);
        uint p = (uint)(unsigned short)f2bf(v.x) | ((uint)(unsigned short)f2bf(v.y) << 16);
        xo[c * (NQ / 2)] = p;
    }
    __shared__ float sf[8][64], sg2[8][64];
    sf[cg][nl] = f0;  sf[cg][nl + 1] = f1;
    sg2[cg][nl] = g0; sg2[cg][nl + 1] = g1;
    __syncthreads();
    if (t < 64) {
        float f = 0.f, gg = 0.f;
#pragma unroll
        for (int i = 0; i < 8; ++i) { f += sf[i][t]; gg += sg2[i][t]; }
        f *= LOG2E;
        fs[b * NQ + blockIdx.x * 64 + t] = f;
        g[b * NQ + blockIdx.x * 64 + t]  = gg;
        float mx = f, mn = f;
#pragma unroll
        for (int off = 32; off; off >>= 1) {
            mx = fmaxf(mx, __shfl_xor(mx, off));
            mn = fminf(mn, __shfl_xor(mn, off));
        }
        if (t == 0) {
            atomicMax(&fmxu[b], fkey(mx));
            atomicMin(&fmnu[b], fkey(mn));
        }
    }
}

// LDS map (bytes):
//   [0, 32768)      : A ring, 2 x 16KB ([256c][64B], 16B slots q-swizzled by (row>>1)&3)
//   [32768, 49152)  : e dbuf, 2 x 8KB ([128m][64B], same 16B-slot swizzle keyed on m)
//   [0, 65536)      : post-loop overlay y_lds (128m x 512B rows, XOR-swizzled)
//   [65536, 67584)  : zpart (4 producers x 128m f32) — above y overlay
#define EOFF 32768
#define ESLOT 8192
#define ZOFF 65536
#define SMEM_BYTES 67584

// stage one 16KB chunk (256c x 32n): linear LDS dest, q-swizzle pre-applied on
// the GLOBAL source (both-sides-or-neither; read side uses the same involution)
#define STAGE(slot, ch)                                                            \
    {                                                                              \
        _Pragma("unroll")                                                          \
        for (int i_ = 0; i_ < 2; ++i_) {                                           \
            int off_ = tid * 16 + i_ * 8192;                                       \
            int row_ = (tid >> 2) + i_ * 128;                                      \
            int slot_ = (tid & 3) ^ ((row_ >> 1) & 3);                             \
            const short* src_ = xb + (size_t)row_ * NQ + (ch) * 32 + slot_ * 8;    \
            __builtin_amdgcn_global_load_lds(                                      \
                (const __attribute__((address_space(1))) void*)src_,               \
                (__attribute__((address_space(3))) void*)(smem + (slot) * 16384 + off_), \
                16, 0, 0);                                                         \
        }                                                                          \
    }

// -------- K2 fused, producer/consumer: y[c][m] = sum_n x[c][n] e[n,m];
//          o = (1-gam)*wv*(y/Z) + gam*x
// 256 blocks (1/CU) x 512 thr (8 waves). Each SIMD: 1 consumer + 1 producer.
// Waves 0..3 = CONSUMERS: wc = w>>1, wm = w&1; tile 128c x 64m (jc=8 x jm=4);
//   pure ds_read + MFMA (no exps).
// Waves 4..7 = PRODUCERS: p = w-4 owns n-slot p (8n) x 128m (2 m per lane);
//   e = exp2(f*g - M) one chunk ahead into e dbuf; Z lane-local.
__global__ void __launch_bounds__(512, 2) k_attn(
    const short* __restrict__ xbf, const float* __restrict__ fsp,
    const float* __restrict__ gp, const uint* __restrict__ fmxu,
    const uint* __restrict__ fmnu, const float* __restrict__ wv,
    const float* __restrict__ x, const float* __restrict__ gamma,
    float* __restrict__ out) {
    __shared__ __align__(16) char smem[SMEM_BYTES];

    int bid = blockIdx.x;
    int b = bid & 7;            // batch -> XCD affinity (2MB xbf slice per XCD L2)
    int mblk = bid >> 3;        // 0..31
    int m0 = mblk * MT;
    int tid = threadIdx.x;
    int l = tid & 63;
    int w = tid >> 6;           // 0..7
    int q = l >> 4;             // k-slot
    int cr = l & 15;            // A-row / B-col within frag
    int qp16 = (q ^ ((cr >> 1) & 3)) * 16;   // swizzled 16B slot (A and e reads)

    const short* xb = xbf + (size_t)b * CQ * NQ;
    const float* fb = fsp + b * NQ;

    // ---- prolog: stage chunk 0 ----
    STAGE(0, 0)

    // consumer state
    int wc = w >> 1;            // c-half
    int wm = w & 1;             // m-half
    f32x4 acc[8][4];
#pragma unroll
    for (int jc = 0; jc < 8; ++jc)
#pragma unroll
        for (int jm = 0; jm < 4; ++jm) acc[jc][jm] = (f32x4){0.f, 0.f, 0.f, 0.f};

    // producer state: p-slot = w-4; two m's per lane (l and l+64)
    int p = w - 4;
    int eslotA = (p ^ ((l >> 1) & 3)) * 16;  // phys slot for both rows (key = (l>>1)&3)
    float gvA = 0.f, gvB = 0.f, nMA = 0.f, nMB = 0.f, zacA = 0.f, zacB = 0.f;
    float4 fca = {0,0,0,0}, fcb = {0,0,0,0}, fna = {0,0,0,0}, fnb = {0,0,0,0};

    if (w >= 4) {
        float fmx = fdec(fmxu[b]), fmn = fdec(fmnu[b]);
        gvA = gp[b * NQ + m0 + l];
        gvB = gp[b * NQ + m0 + l + 64];
        nMA = -((gvA >= 0.f) ? gvA * fmx : gvA * fmn);
        nMB = -((gvB >= 0.f) ? gvB * fmx : gvB * fmn);
        // e(0): direct f load, compute both m-rows, write e dbuf slot 0
        float4 a0 = ld4(fb + p * 8);
        float4 b0 = ld4(fb + p * 8 + 4);
        float fq[8] = {a0.x, a0.y, a0.z, a0.w, b0.x, b0.y, b0.z, b0.w};
        s16x8 evA, evB;
#pragma unroll
        for (int i = 0; i < 8; ++i) {
            float eA = __builtin_amdgcn_exp2f(fmaf(fq[i], gvA, nMA));
            float eB = __builtin_amdgcn_exp2f(fmaf(fq[i], gvB, nMB));
            zacA += eA; zacB += eB;
            evA[i] = f2bf(eA); evB[i] = f2bf(eB);
        }
        *(s16x8*)(smem + EOFF + l * 64 + eslotA) = evA;
        *(s16x8*)(smem + EOFF + (l + 64) * 64 + eslotA) = evB;
        // prefetch f for chunks 1 and 2
        fca = ld4(fb + 32 + p * 8);  fcb = ld4(fb + 32 + p * 8 + 4);
        fna = ld4(fb + 64 + p * 8);  fnb = ld4(fb + 64 + p * 8 + 4);
    }
    __syncthreads();   // ring(0) + e(0) ready

    for (int s = 0; s < NCH; ++s) {
        if (s + 1 < NCH) STAGE((s + 1) & 1, s + 1)   // lands before end barrier
        if (w < 4) {
            // ---- consumer: 4 B-frags from e dbuf, 8 A-frags from ring, 32 MFMA ----
            const char* cbuf = smem + (s & 1) * 16384;
            const char* ebuf = smem + EOFF + (s & 1) * ESLOT;
            s16x8 bv[4];
#pragma unroll
            for (int jm = 0; jm < 4; ++jm)
                bv[jm] = *(const s16x8*)(ebuf + (wm * 64 + jm * 16 + cr) * 64 + qp16);
#pragma unroll
            for (int jc = 0; jc < 8; ++jc) {
                s16x8 av = *(const s16x8*)(cbuf + (wc * 128 + jc * 16 + cr) * 64 + qp16);
#pragma unroll
                for (int jm = 0; jm < 4; ++jm)
                    acc[jc][jm] = __builtin_amdgcn_mfma_f32_16x16x32_bf16(av, bv[jm], acc[jc][jm], 0, 0, 0);
            }
        } else if (s + 1 < NCH) {
            // ---- producer: e(s+1) into dbuf slot (s+1)&1, rotate f prefetch ----
            char* ebuf = smem + EOFF + ((s + 1) & 1) * ESLOT;
            float fq[8] = {fca.x, fca.y, fca.z, fca.w, fcb.x, fcb.y, fcb.z, fcb.w};
            s16x8 evA, evB;
#pragma unroll
            for (int i = 0; i < 8; ++i) {
                float eA = __builtin_amdgcn_exp2f(fmaf(fq[i], gvA, nMA));
                float eB = __builtin_amdgcn_exp2f(fmaf(fq[i], gvB, nMB));
                zacA += eA; zacB += eB;
                evA[i] = f2bf(eA); evB[i] = f2bf(eB);
            }
            *(s16x8*)(ebuf + l * 64 + eslotA) = evA;
            *(s16x8*)(ebuf + (l + 64) * 64 + eslotA) = evB;
            fca = fna; fcb = fnb;
            int ch = (s + 3) & (NCH - 1);
            fna = ld4(fb + ch * 32 + p * 8);
            fnb = ld4(fb + ch * 32 + p * 8 + 4);
        }
        __syncthreads();   // ring(s+1) + e(s+1) landed; slot s freed
    }

    // ---- Z: producers publish lane-local sums ----
    if (w >= 4) {
        float* zb = (float*)(smem + ZOFF);
        zb[p * 128 + l] = zacA;
        zb[p * 128 + l + 64] = zacB;
    }
    __syncthreads();

    // ---- y_norm -> LDS (consumers): y_lds[m][c] bf16, 512B rows, XOR-swizzled ----
    if (w < 4) {
        const float* zb = (const float*)(smem + ZOFF);
        float rzl[4];
#pragma unroll
        for (int jm = 0; jm < 4; ++jm) {
            int mloc = wm * 64 + jm * 16 + cr;
            float z = zb[mloc] + zb[128 + mloc] + zb[256 + mloc] + zb[384 + mloc];
            rzl[jm] = 1.0f / z;
        }
#pragma unroll
        for (int jc = 0; jc < 8; ++jc) {
#pragma unroll
            for (int jm = 0; jm < 4; ++jm) {
                int mloc = wm * 64 + jm * 16 + cr;
                int cb = (wc * 256 + jc * 32 + q * 8) ^ ((mloc & 7) << 4);
                s16x4 v;
#pragma unroll
                for (int r = 0; r < 4; ++r) v[r] = f2bf(acc[jc][jm][r] * rzl[jm]);
                *(s16x4*)(smem + mloc * 512 + cb) = v;
            }
        }
    }
    __syncthreads();

    // ---- GEMM2: o[c_out][m] = wv[c_out][:] . y_norm[:][m], K=256 (all 8 waves) ----
    int co0 = w * 32;
    f32x4 acc2[2][8];
#pragma unroll
    for (int j2 = 0; j2 < 2; ++j2)
#pragma unroll
        for (int jm2 = 0; jm2 < 8; ++jm2) acc2[j2][jm2] = (f32x4){0.f, 0.f, 0.f, 0.f};

#pragma unroll 2
    for (int ks = 0; ks < 8; ++ks) {
        s16x8 a2[2];
#pragma unroll
        for (int j2 = 0; j2 < 2; ++j2) {
            const float* wr = wv + (size_t)(co0 + j2 * 16 + cr) * CQ + ks * 32 + q * 8;
            float4 wa = ld4(wr);
            float4 wb = ld4(wr + 4);
            a2[j2][0] = f2bf(wa.x); a2[j2][1] = f2bf(wa.y);
            a2[j2][2] = f2bf(wa.z); a2[j2][3] = f2bf(wa.w);
            a2[j2][4] = f2bf(wb.x); a2[j2][5] = f2bf(wb.y);
            a2[j2][6] = f2bf(wb.z); a2[j2][7] = f2bf(wb.w);
        }
#pragma unroll
        for (int jm2 = 0; jm2 < 8; ++jm2) {
            int mloc = jm2 * 16 + cr;
            s16x8 b2 = *(const s16x8*)(smem + mloc * 512 + ((ks * 64 + q * 16) ^ ((mloc & 7) << 4)));
#pragma unroll
            for (int j2 = 0; j2 < 2; ++j2)
                acc2[j2][jm2] = __builtin_amdgcn_mfma_f32_16x16x32_bf16(a2[j2], b2, acc2[j2][jm2], 0, 0, 0);
        }
    }

    // ---- epilogue ----
    float gam = gamma[0];
    float omg = 1.f - gam;
    if (gam != 0.f) {
#pragma unroll
        for (int j2 = 0; j2 < 2; ++j2)
#pragma unroll
            for (int jm2 = 0; jm2 < 8; ++jm2)
#pragma unroll
                for (int r = 0; r < 4; ++r) {
                    int c_out = co0 + j2 * 16 + q * 4 + r;
                    size_t idx = ((size_t)b * CQ + c_out) * NQ + m0 + jm2 * 16 + cr;
                    __builtin_nontemporal_store(
                        fmaf(gam, x[idx], acc2[j2][jm2][r] * omg), out + idx);
                }
    } else {
#pragma unroll
        for (int j2 = 0; j2 < 2; ++j2)
#pragma unroll
            for (int jm2 = 0; jm2 < 8; ++jm2)
#pragma unroll
                for (int r = 0; r < 4; ++r) {
                    int c_out = co0 + j2 * 16 + q * 4 + r;
                    size_t idx = ((size_t)b * CQ + c_out) * NQ + m0 + jm2 * 16 + cr;
                    __builtin_nontemporal_store(acc2[j2][jm2][r] * omg, out + idx);
                }
    }
}

extern "C" void kernel_launch(void* const* d_in, const int* in_sizes, int n_in,
                              void* d_out, int out_size, void* d_ws, size_t ws_size,
                              hipStream_t stream) {
    const float* x     = (const float*)d_in[0];
    const float* wq    = (const float*)d_in[1];
    const float* wk    = (const float*)d_in[2];
    const float* wv    = (const float*)d_in[3];
    const float* gamma = (const float*)d_in[4];
    float* out = (float*)d_out;

    // ws (floats): fs[B*N] | g[B*N] | fmxu[8]+fmnu[8] (uint) | pad -> xbf (bf16) [B*C*N]
    float* ws  = (float*)d_ws;
    float* fs  = ws;
    float* g   = ws + BQ * NQ;
    uint* fmxu = (uint*)(ws + 2 * BQ * NQ);
    uint* fmnu = fmxu + 8;
    short* xbf = (short*)(ws + 2 * BQ * NQ + 64);

    hipMemsetAsync(fmxu, 0x00, 32, stream);   // lowest key
    hipMemsetAsync(fmnu, 0xFF, 32, stream);   // highest key
    hipLaunchKernelGGL(k_fg, dim3(NQ / 64, BQ), dim3(256), 0, stream,
                       x, wq, wk, fs, g, xbf, fmxu, fmnu);
    hipLaunchKernelGGL(k_attn, dim3(BQ * (NQ / MT)), dim3(512), 0, stream,
                       xbf, fs, g, fmxu, fmnu, wv, x, gamma, out);
}

// Round 11
// 123.475 us; speedup vs baseline: 1.1532x; 1.1532x over previous
//
#include <hip/hip_runtime.h>
#include <math.h>

// Problem constants (B,C,H,W = 8,256,64,64; N = H*W = 4096)
#define BQ 8
#define CQ 256
#define NQ 4096
#define MT 128            // m-tile per block -> 256 blocks, 1/CU
#define NSUP 64           // supersteps (2 chunks of 32n each)

typedef short s16x8 __attribute__((ext_vector_type(8)));
typedef short s16x4 __attribute__((ext_vector_type(4)));
typedef float f32x4 __attribute__((ext_vector_type(4)));
typedef unsigned int uint;

static __device__ __forceinline__ float4 ld4(const float* p) { return *(const float4*)p; }

static constexpr float LOG2E = 1.4426950408889634f;

static __device__ __forceinline__ short f2bf(float f) {
    return __builtin_bit_cast(short, (__bf16)f);
}
// monotonic uint key for float compare via atomicMax/Min
static __device__ __forceinline__ uint fkey(float f) {
    uint b = __builtin_bit_cast(uint, f);
    return b ^ (0x80000000u | (uint)((int)b >> 31));
}
static __device__ __forceinline__ float fdec(uint u) {
    uint b = (u & 0x80000000u) ? (u ^ 0x80000000u) : ~u;
    return __builtin_bit_cast(float, b);
}

// -------- K1: f' = (wq.x)*log2e, g = wk.x, xbf = bf16(x), fused batch max/min --------
__global__ void k_fg(const float* __restrict__ x, const float* __restrict__ wq,
                     const float* __restrict__ wk, float* __restrict__ fs,
                     float* __restrict__ g, short* __restrict__ xbf,
                     uint* __restrict__ fmxu, uint* __restrict__ fmnu) {
    int b = blockIdx.y;
    int t = threadIdx.x;
    int nl = (t & 31) * 2;
    int cg = t >> 5;                     // 0..7
    int n = blockIdx.x * 64 + nl;
    const float* xb = x + (size_t)b * CQ * NQ + n;
    uint* xo = (uint*)(xbf + (size_t)b * CQ * NQ + n);
    float f0 = 0.f, f1 = 0.f, g0 = 0.f, g1 = 0.f;
    int c0 = cg * 32;
#pragma unroll 8
    for (int c = c0; c < c0 + 32; ++c) {
        float2 v = *(const float2*)&xb[(size_t)c * NQ];
        f0 = fmaf(wq[c], v.x, f0);
        f1 = fmaf(wq[c], v.y, f1);
        g0 = fmaf(wk[c], v.x, g0);
        g1 = fmaf(wk[c], v.y, g1);
        uint p = (uint)(unsigned short)f2bf(v.x) | ((uint)(unsigned short)f2bf(v.y) << 16);
        xo[c * (NQ / 2)] = p;
    }
    __shared__ float sf[8][64], sg2[8][64];
    sf[cg][nl] = f0;  sf[cg][nl + 1] = f1;
    sg2[cg][nl] = g0; sg2[cg][nl + 1] = g1;
    __syncthreads();
    if (t < 64) {
        float f = 0.f, gg = 0.f;
#pragma unroll
        for (int i = 0; i < 8; ++i) { f += sf[i][t]; gg += sg2[i][t]; }
        f *= LOG2E;
        fs[b * NQ + blockIdx.x * 64 + t] = f;
        g[b * NQ + blockIdx.x * 64 + t]  = gg;
        float mx = f, mn = f;
#pragma unroll
        for (int off = 32; off; off >>= 1) {
            mx = fmaxf(mx, __shfl_xor(mx, off));
            mn = fminf(mn, __shfl_xor(mn, off));
        }
        if (t == 0) {
            atomicMax(&fmxu[b], fkey(mx));
            atomicMin(&fmnu[b], fkey(mn));
        }
    }
}

// LDS map (bytes):
//   [0, 98304)        : ring, 6 x 16KB chunk slots (256c x 32n bf16, 16B-slot q-swizzled)
//   [98304, 114688)   : f_lds (4096 f32)
//   [0, 131072)       : post-loop merge overlay (8 pairs x 16KB f32)
//   [131072, 133120)  : zbuf (16 waves x 32 f32)
//   [0, 65536)        : post-merge y_lds overlay (128m x 512B rows, XOR-swizzled)
#define FLDS_OFF 98304
#define ZBUF_OFF 131072
#define SMEM_BYTES 133120

// -------- K2 fused: y[c][m] = sum_n x[c][n] e[n,m];  o = (1-gam)*wv*(y/Z) + gam*x --------
// 256 blocks (1/CU) x 1024 thr, 16 waves: ws = w&1 (chunk parity), wm = (w>>1)&3
// (m-quarter), wc = w>>3 (c-half). Wave tile 128c x 32m (jc=8 x jm=2).
// T3/T4: 6-deep chunk ring, counted s_waitcnt vmcnt(2) + raw s_barrier — stage
// loads for pairs p+1/p+2 stay in flight ACROSS barriers (no vmcnt(0) drain).
// T5: setprio(1) around the MFMA cluster. Z via MFMA with A = ones (matrix pipe).
__global__ void __launch_bounds__(1024, 4) k_attn(
    const short* __restrict__ xbf, const float* __restrict__ fsp,
    const float* __restrict__ gp, const uint* __restrict__ fmxu,
    const uint* __restrict__ fmnu, const float* __restrict__ wv,
    const float* __restrict__ x, const float* __restrict__ gamma,
    float* __restrict__ out) {
    __shared__ __align__(16) char smem[SMEM_BYTES];

    int bid = blockIdx.x;
    int b = bid & 7;            // batch -> XCD affinity (2MB xbf slice per XCD L2)
    int mblk = bid >> 3;        // 0..31
    int m0 = mblk * MT;
    int tid = threadIdx.x;
    int l = tid & 63;
    int w = tid >> 6;           // 0..15
    int ws = w & 1;             // chunk parity
    int wm = (w >> 1) & 3;      // m-quarter
    int wc = w >> 3;            // c-half
    int q = l >> 4;             // k-slot
    int cr = l & 15;            // A-row / B-col within frag
    int qp16 = (q ^ ((cr >> 1) & 3)) * 16;   // swizzled 16B slot for A-reads

    const short* xb = xbf + (size_t)b * CQ * NQ;
    const float* fb = fsp + b * NQ;

    // hoisted stage addressing: 1024 thr x 16B = one 16KB chunk per issue
    int srow = tid >> 2;                      // 0..255 (c row)
    int sl = (tid & 3) ^ ((srow >> 1) & 3);   // q-swizzle pre-applied on global src
    const short* srcb = xb + (size_t)srow * NQ + sl * 8;
    int dst = tid * 16;

    // ---- prologue: stage f (1 load) + chunks 0..3 (4 loads) ----
    __builtin_amdgcn_global_load_lds(
        (const __attribute__((address_space(1))) void*)(fb + tid * 4),
        (__attribute__((address_space(3))) void*)(smem + FLDS_OFF + dst), 16, 0, 0);
#pragma unroll
    for (int k = 0; k < 4; ++k) {
        __builtin_amdgcn_global_load_lds(
            (const __attribute__((address_space(1))) void*)(srcb + k * 32),
            (__attribute__((address_space(3))) void*)(smem + k * 16384 + dst), 16, 0, 0);
    }

    float fmx = fdec(fmxu[b]), fmn = fdec(fmnu[b]);
    const float* gb = gp + b * NQ;
    float gj[2], nM[2];
#pragma unroll
    for (int jm = 0; jm < 2; ++jm) {
        float gv = gb[m0 + wm * 32 + jm * 16 + cr];
        gj[jm] = gv;
        nM[jm] = -((gv >= 0.f) ? gv * fmx : gv * fmn);
    }
    // ones A-frag for Z-accumulation MFMA (bf16 1.0 = 0x3F80)
    s16x8 ones;
#pragma unroll
    for (int i = 0; i < 8; ++i) ones[i] = (short)0x3F80;

    f32x4 acc[8][2];
#pragma unroll
    for (int jc = 0; jc < 8; ++jc)
#pragma unroll
        for (int jm = 0; jm < 2; ++jm) acc[jc][jm] = (f32x4){0.f, 0.f, 0.f, 0.f};
    f32x4 accz[2] = {(f32x4){0.f, 0.f, 0.f, 0.f}, (f32x4){0.f, 0.f, 0.f, 0.f}};

    // f landed (FIFO: oldest of 5) -> fq_cur readable
    asm volatile("s_waitcnt vmcnt(4)" ::: "memory");
    __builtin_amdgcn_s_barrier();
    const float* fl0 = (const float*)(smem + FLDS_OFF);
    float4 fqa = *(const float4*)(fl0 + ws * 32 + q * 8);
    float4 fqb = *(const float4*)(fl0 + ws * 32 + q * 8 + 4);

    int rs = 0;    // ring slot of chunk 2p
    int ssl = 4;   // ring slot of chunk 2p+4
    for (int p = 0; p < NSUP; ++p) {
        // pair p landed (pairs p+1 [2 loads] allowed in flight) -> tile complete
        asm volatile("s_waitcnt vmcnt(2)" ::: "memory");
        __builtin_amdgcn_s_barrier();
        // stage pair p+2 (wrapped at tail for uniform vmcnt; slots never re-read)
        {
            int chA = (2 * p + 4) & 127;
            __builtin_amdgcn_global_load_lds(
                (const __attribute__((address_space(1))) void*)(srcb + chA * 32),
                (__attribute__((address_space(3))) void*)(smem + ssl * 16384 + dst), 16, 0, 0);
            __builtin_amdgcn_global_load_lds(
                (const __attribute__((address_space(1))) void*)(srcb + (chA + 1) * 32),
                (__attribute__((address_space(3))) void*)(smem + (ssl + 1) * 16384 + dst), 16, 0, 0);
        }
        // ---- e-gen (registers) ----
        float fq[8] = {fqa.x, fqa.y, fqa.z, fqa.w, fqb.x, fqb.y, fqb.z, fqb.w};
        s16x8 bv[2];
#pragma unroll
        for (int jm = 0; jm < 2; ++jm) {
#pragma unroll
            for (int i = 0; i < 8; ++i)
                bv[jm][i] = f2bf(__builtin_amdgcn_exp2f(fmaf(fq[i], gj[jm], nM[jm])));
        }
        // Z on the matrix pipe
        accz[0] = __builtin_amdgcn_mfma_f32_16x16x32_bf16(ones, bv[0], accz[0], 0, 0, 0);
        accz[1] = __builtin_amdgcn_mfma_f32_16x16x32_bf16(ones, bv[1], accz[1], 0, 0, 0);
        // prefetch next superstep's f (independent of MFMA cluster)
        {
            int cn = (2 * p + 2 + ws) & 127;
            fqa = *(const float4*)(fl0 + cn * 32 + q * 8);
            fqb = *(const float4*)(fl0 + cn * 32 + q * 8 + 4);
        }
        // ---- MFMA cluster (T5) ----
        const char* cbuf = smem + (rs + ws) * 16384;
        __builtin_amdgcn_s_setprio(1);
#pragma unroll
        for (int jc = 0; jc < 8; ++jc) {
            s16x8 av = *(const s16x8*)(cbuf + (wc * 128 + jc * 16 + cr) * 64 + qp16);
            acc[jc][0] = __builtin_amdgcn_mfma_f32_16x16x32_bf16(av, bv[0], acc[jc][0], 0, 0, 0);
            acc[jc][1] = __builtin_amdgcn_mfma_f32_16x16x32_bf16(av, bv[1], acc[jc][1], 0, 0, 0);
        }
        __builtin_amdgcn_s_setprio(0);
        rs += 2;  if (rs >= 6) rs -= 6;
        ssl += 2; if (ssl >= 6) ssl -= 6;
    }
    __syncthreads();   // full drain (incl. wrap stages) before overlays

    // ---- Z + acc merge across ws pairs ----
    float zf[2] = {accz[0][0], accz[1][0]};
    {
        float* zb = (float*)(smem + ZBUF_OFF);
        if (q == 0) {
#pragma unroll
            for (int jm = 0; jm < 2; ++jm) zb[w * 32 + jm * 16 + cr] = zf[jm];
        }
        int p8 = wc * 4 + wm;
        float* mrg = (float*)(smem + p8 * 16384);
        if (ws == 1) {
#pragma unroll
            for (int jc = 0; jc < 8; ++jc)
#pragma unroll
                for (int jm = 0; jm < 2; ++jm)
                    *(f32x4*)(mrg + ((jc * 2 + jm) * 64 + l) * 4) = acc[jc][jm];
        }
        __syncthreads();
        if (ws == 0) {
#pragma unroll
            for (int jc = 0; jc < 8; ++jc)
#pragma unroll
                for (int jm = 0; jm < 2; ++jm) {
                    f32x4 o = *(const f32x4*)(mrg + ((jc * 2 + jm) * 64 + l) * 4);
                    acc[jc][jm] += o;
                }
        }
#pragma unroll
        for (int jm = 0; jm < 2; ++jm) zf[jm] += zb[(w ^ 1) * 32 + jm * 16 + cr];
        __syncthreads();   // merge reads done before y_lds overwrites region
    }

    // ---- y_norm -> LDS (ws0 waves): y_lds[m][c] bf16, 512B rows, XOR-swizzled ----
    if (ws == 0) {
        float rzl[2];
#pragma unroll
        for (int jm = 0; jm < 2; ++jm) rzl[jm] = 1.0f / zf[jm];
#pragma unroll
        for (int jc = 0; jc < 8; ++jc) {
#pragma unroll
            for (int jm = 0; jm < 2; ++jm) {
                int mloc = wm * 32 + jm * 16 + cr;
                int cb = (wc * 256 + jc * 32 + q * 8) ^ ((mloc & 7) << 4);
                s16x4 v;
#pragma unroll
                for (int r = 0; r < 4; ++r) v[r] = f2bf(acc[jc][jm][r] * rzl[jm]);
                *(s16x4*)(smem + mloc * 512 + cb) = v;
            }
        }
    }
    __syncthreads();

    // ---- GEMM2: o[c_out][m] = wv[c_out][:] . y_norm[:][m], K=256 (16 waves) ----
    int co0 = w * 16;
    f32x4 acc2[8];
#pragma unroll
    for (int jm2 = 0; jm2 < 8; ++jm2) acc2[jm2] = (f32x4){0.f, 0.f, 0.f, 0.f};

#pragma unroll 2
    for (int ks = 0; ks < 8; ++ks) {
        s16x8 a2;
        {
            const float* wr = wv + (size_t)(co0 + cr) * CQ + ks * 32 + q * 8;
            float4 wa = ld4(wr);
            float4 wb = ld4(wr + 4);
            a2[0] = f2bf(wa.x); a2[1] = f2bf(wa.y);
            a2[2] = f2bf(wa.z); a2[3] = f2bf(wa.w);
            a2[4] = f2bf(wb.x); a2[5] = f2bf(wb.y);
            a2[6] = f2bf(wb.z); a2[7] = f2bf(wb.w);
        }
#pragma unroll
        for (int jm2 = 0; jm2 < 8; ++jm2) {
            int mloc = jm2 * 16 + cr;
            s16x8 b2 = *(const s16x8*)(smem + mloc * 512 + ((ks * 64 + q * 16) ^ ((mloc & 7) << 4)));
            acc2[jm2] = __builtin_amdgcn_mfma_f32_16x16x32_bf16(a2, b2, acc2[jm2], 0, 0, 0);
        }
    }

    // ---- epilogue ----
    float gam = gamma[0];
    float omg = 1.f - gam;
    if (gam != 0.f) {
#pragma unroll
        for (int jm2 = 0; jm2 < 8; ++jm2)
#pragma unroll
            for (int r = 0; r < 4; ++r) {
                int c_out = co0 + q * 4 + r;
                size_t idx = ((size_t)b * CQ + c_out) * NQ + m0 + jm2 * 16 + cr;
                __builtin_nontemporal_store(
                    fmaf(gam, x[idx], acc2[jm2][r] * omg), out + idx);
            }
    } else {
#pragma unroll
        for (int jm2 = 0; jm2 < 8; ++jm2)
#pragma unroll
            for (int r = 0; r < 4; ++r) {
                int c_out = co0 + q * 4 + r;
                size_t idx = ((size_t)b * CQ + c_out) * NQ + m0 + jm2 * 16 + cr;
                __builtin_nontemporal_store(acc2[jm2][r] * omg, out + idx);
            }
    }
}

extern "C" void kernel_launch(void* const* d_in, const int* in_sizes, int n_in,
                              void* d_out, int out_size, void* d_ws, size_t ws_size,
                              hipStream_t stream) {
    const float* x     = (const float*)d_in[0];
    const float* wq    = (const float*)d_in[1];
    const float* wk    = (const float*)d_in[2];
    const float* wv    = (const float*)d_in[3];
    const float* gamma = (const float*)d_in[4];
    float* out = (float*)d_out;

    // ws (floats): fs[B*N] | g[B*N] | fmxu[8]+fmnu[8] (uint) | pad -> xbf (bf16) [B*C*N]
    float* ws  = (float*)d_ws;
    float* fs  = ws;
    float* g   = ws + BQ * NQ;
    uint* fmxu = (uint*)(ws + 2 * BQ * NQ);
    uint* fmnu = fmxu + 8;
    short* xbf = (short*)(ws + 2 * BQ * NQ + 64);

    hipMemsetAsync(fmxu, 0x00, 32, stream);   // lowest key
    hipMemsetAsync(fmnu, 0xFF, 32, stream);   // highest key
    hipLaunchKernelGGL(k_fg, dim3(NQ / 64, BQ), dim3(256), 0, stream,
                       x, wq, wk, fs, g, xbf, fmxu, fmnu);
    hipLaunchKernelGGL(k_attn, dim3(BQ * (NQ / MT)), dim3(1024), 0, stream,
                       xbf, fs, g, fmxu, fmnu, wv, x, gamma, out);
}

// Round 12
// 121.916 us; speedup vs baseline: 1.1680x; 1.0128x over previous
//
#include <hip/hip_runtime.h>
#include <math.h>

// Problem constants (B,C,H,W = 8,256,64,64; N = H*W = 4096)
#define BQ 8
#define CQ 256
#define NQ 4096
#define MT 128            // m-tile per block -> 256 blocks, 1/CU
#define NSUP 64           // supersteps (2 chunks of 32n each)

typedef short s16x8 __attribute__((ext_vector_type(8)));
typedef short s16x4 __attribute__((ext_vector_type(4)));
typedef float f32x4 __attribute__((ext_vector_type(4)));
typedef float f32x16 __attribute__((ext_vector_type(16)));
typedef unsigned int uint;

static __device__ __forceinline__ float4 ld4(const float* p) { return *(const float4*)p; }

static constexpr float LOG2E = 1.4426950408889634f;

static __device__ __forceinline__ short f2bf(float f) {
    return __builtin_bit_cast(short, (__bf16)f);
}
// monotonic uint key for float compare via atomicMax/Min
static __device__ __forceinline__ uint fkey(float f) {
    uint b = __builtin_bit_cast(uint, f);
    return b ^ (0x80000000u | (uint)((int)b >> 31));
}
static __device__ __forceinline__ float fdec(uint u) {
    uint b = (u & 0x80000000u) ? (u ^ 0x80000000u) : ~u;
    return __builtin_bit_cast(float, b);
}

// -------- K1: f' = (wq.x)*log2e, g = wk.x, xbf = bf16(x), fused batch max/min --------
__global__ void k_fg(const float* __restrict__ x, const float* __restrict__ wq,
                     const float* __restrict__ wk, float* __restrict__ fs,
                     float* __restrict__ g, short* __restrict__ xbf,
                     uint* __restrict__ fmxu, uint* __restrict__ fmnu) {
    int b = blockIdx.y;
    int t = threadIdx.x;
    int nl = (t & 31) * 2;
    int cg = t >> 5;                     // 0..7
    int n = blockIdx.x * 64 + nl;
    const float* xb = x + (size_t)b * CQ * NQ + n;
    uint* xo = (uint*)(xbf + (size_t)b * CQ * NQ + n);
    float f0 = 0.f, f1 = 0.f, g0 = 0.f, g1 = 0.f;
    int c0 = cg * 32;
#pragma unroll 8
    for (int c = c0; c < c0 + 32; ++c) {
        float2 v = *(const float2*)&xb[(size_t)c * NQ];
        f0 = fmaf(wq[c], v.x, f0);
        f1 = fmaf(wq[c], v.y, f1);
        g0 = fmaf(wk[c], v.x, g0);
        g1 = fmaf(wk[c], v.y, g1);
        uint p = (uint)(unsigned short)f2bf(v.x) | ((uint)(unsigned short)f2bf(v.y) << 16);
        xo[c * (NQ / 2)] = p;
    }
    __shared__ float sf[8][64], sg2[8][64];
    sf[cg][nl] = f0;  sf[cg][nl + 1] = f1;
    sg2[cg][nl] = g0; sg2[cg][nl + 1] = g1;
    __syncthreads();
    if (t < 64) {
        float f = 0.f, gg = 0.f;
#pragma unroll
        for (int i = 0; i < 8; ++i) { f += sf[i][t]; gg += sg2[i][t]; }
        f *= LOG2E;
        fs[b * NQ + blockIdx.x * 64 + t] = f;
        g[b * NQ + blockIdx.x * 64 + t]  = gg;
        float mx = f, mn = f;
#pragma unroll
        for (int off = 32; off; off >>= 1) {
            mx = fmaxf(mx, __shfl_xor(mx, off));
            mn = fminf(mn, __shfl_xor(mn, off));
        }
        if (t == 0) {
            atomicMax(&fmxu[b], fkey(mx));
            atomicMin(&fmnu[b], fkey(mn));
        }
    }
}

// LDS map (bytes):
//   [0, 98304)        : ring, 6 x 16KB chunk slots (256c x 32n bf16, 16B-slot q-swizzled)
//   [98304, 114688)   : f_lds (4096 f32)
//   [0, 131072)       : post-loop merge overlay (4 ws-pairs x 32KB f32)
//   [131072, 133120)  : zbuf (8 waves x 64 m f32)
//   [0, 65536)        : post-merge y_lds overlay (128m x 512B rows, XOR-swizzled)
#define FLDS_OFF 98304
#define ZBUF_OFF 131072
#define SMEM_BYTES 133120

#define GSRC(p) (const __attribute__((address_space(1))) void*)(p)
#define LDST(p) (__attribute__((address_space(3))) void*)(p)

// -------- K2 fused: y[c][m] = sum_n x[c][n] e[n,m];  o = (1-gam)*wv*(y/Z) + gam*x --------
// 256 blocks (1/CU) x 512 thr, 8 waves: ws = w&1 (chunk parity), wm = (w>>1)&1
// (m-half), wc = w>>2 (c-half). Wave tile 128c x 64m on mfma_f32_32x32x16_bf16:
// 4 c-tiles x 2 m-tiles, acc = 8 x f32x16 = 128 VGPR (2 waves/SIMD, 256 cap).
// Counted s_waitcnt vmcnt(4) + raw s_barrier: stage pairs p+1/p+2 in flight across
// barriers. e B-frags generated in registers; Z on VALU (+ shfl_xor 32 at end).
__global__ void __launch_bounds__(512, 2) k_attn(
    const short* __restrict__ xbf, const float* __restrict__ fsp,
    const float* __restrict__ gp, const uint* __restrict__ fmxu,
    const uint* __restrict__ fmnu, const float* __restrict__ wv,
    const float* __restrict__ x, const float* __restrict__ gamma,
    float* __restrict__ out) {
    __shared__ __align__(16) char smem[SMEM_BYTES];

    int bid = blockIdx.x;
    int b = bid & 7;            // batch -> XCD affinity (2MB xbf slice per XCD L2)
    int mblk = bid >> 3;        // 0..31
    int m0 = mblk * MT;
    int tid = threadIdx.x;
    int l = tid & 63;
    int w = tid >> 6;           // 0..7
    int ws = w & 1;             // chunk parity
    int wm = (w >> 1) & 1;      // m-half
    int wc = w >> 2;            // c-half
    int col = l & 31;           // 32x32 A-row / B-col within tile
    int hi = l >> 5;            // k-half selector
    int q = l >> 4;             // 16x16 k-slot (GEMM2)
    int cr = l & 15;            // 16x16 row/col (GEMM2)

    const short* xb = xbf + (size_t)b * CQ * NQ;
    const float* fb = fsp + b * NQ;

    // stage addressing: 512 thr x 16B x 2 issues = one 16KB chunk
    int dst = tid * 16;
    int srow0 = tid >> 2;                 // rows 0..127
    int srow1 = srow0 + 128;              // rows 128..255
    const short* src0 = xb + (size_t)srow0 * NQ + ((tid & 3) ^ ((srow0 >> 1) & 3)) * 8;
    const short* src1 = xb + (size_t)srow1 * NQ + ((tid & 3) ^ ((srow1 >> 1) & 3)) * 8;

    // ---- prologue: stage f (2 loads) + chunks 0..3 (8 loads) ----
    __builtin_amdgcn_global_load_lds(GSRC(fb + tid * 4),
        LDST(smem + FLDS_OFF + dst), 16, 0, 0);
    __builtin_amdgcn_global_load_lds(GSRC(fb + tid * 4 + 2048),
        LDST(smem + FLDS_OFF + 8192 + dst), 16, 0, 0);
#pragma unroll
    for (int k = 0; k < 4; ++k) {
        __builtin_amdgcn_global_load_lds(GSRC(src0 + k * 32),
            LDST(smem + k * 16384 + dst), 16, 0, 0);
        __builtin_amdgcn_global_load_lds(GSRC(src1 + k * 32),
            LDST(smem + k * 16384 + 8192 + dst), 16, 0, 0);
    }

    float fmx = fdec(fmxu[b]), fmn = fdec(fmnu[b]);
    const float* gb = gp + b * NQ;
    float gj[2], nM[2], zac[2] = {0.f, 0.f};
#pragma unroll
    for (int mt = 0; mt < 2; ++mt) {
        float gv = gb[m0 + wm * 64 + mt * 32 + col];
        gj[mt] = gv;
        nM[mt] = -((gv >= 0.f) ? gv * fmx : gv * fmn);
    }

    // A-read addressing: row = wc*128 + ct*32 + col; phys16B = (kt*2+hi) ^ ((row>>1)&3)
    int rowoff[4], rkey[4];
#pragma unroll
    for (int ct = 0; ct < 4; ++ct) {
        int row = wc * 128 + ct * 32 + col;
        rowoff[ct] = row * 64;
        rkey[ct] = ((row >> 1) & 3) * 16;
    }

    f32x16 acc[4][2];
#pragma unroll
    for (int ct = 0; ct < 4; ++ct)
#pragma unroll
        for (int mt = 0; mt < 2; ++mt)
#pragma unroll
            for (int r = 0; r < 16; ++r) acc[ct][mt][r] = 0.f;

    // f landed (oldest 2 of 10) -> safe after barrier
    asm volatile("s_waitcnt vmcnt(8)" ::: "memory");
    __builtin_amdgcn_s_barrier();
    const float* fl0 = (const float*)(smem + FLDS_OFF);
    float4 fc[4];
    {
        int n0 = ws * 32;
        fc[0] = *(const float4*)(fl0 + n0 + 8 * hi);
        fc[1] = *(const float4*)(fl0 + n0 + 8 * hi + 4);
        fc[2] = *(const float4*)(fl0 + n0 + 16 + 8 * hi);
        fc[3] = *(const float4*)(fl0 + n0 + 16 + 8 * hi + 4);
    }

    int rs = 0;    // ring slot of chunk 2p
    int ssl = 4;   // ring slot target for chunk 2p+4
    for (int p = 0; p < NSUP; ++p) {
        // pair p landed; pair p+1 (4 loads) stays in flight across the barrier
        asm volatile("s_waitcnt vmcnt(4)" ::: "memory");
        __builtin_amdgcn_s_barrier();
        // stage pair p+2 (wrapped at tail for uniform vmcnt; slots never re-read)
        {
            int chA = (2 * p + 4) & 127;
            __builtin_amdgcn_global_load_lds(GSRC(src0 + chA * 32),
                LDST(smem + ssl * 16384 + dst), 16, 0, 0);
            __builtin_amdgcn_global_load_lds(GSRC(src1 + chA * 32),
                LDST(smem + ssl * 16384 + 8192 + dst), 16, 0, 0);
            __builtin_amdgcn_global_load_lds(GSRC(src0 + chA * 32 + 32),
                LDST(smem + (ssl + 1) * 16384 + dst), 16, 0, 0);
            __builtin_amdgcn_global_load_lds(GSRC(src1 + chA * 32 + 32),
                LDST(smem + (ssl + 1) * 16384 + 8192 + dst), 16, 0, 0);
        }
        // ---- e-gen: 4 B-frags (2 mt x 2 kt) in registers + running Z ----
        s16x8 bv[2][2];
#pragma unroll
        for (int kt = 0; kt < 2; ++kt) {
            float fq[8] = {fc[kt*2].x, fc[kt*2].y, fc[kt*2].z, fc[kt*2].w,
                           fc[kt*2+1].x, fc[kt*2+1].y, fc[kt*2+1].z, fc[kt*2+1].w};
#pragma unroll
            for (int mt = 0; mt < 2; ++mt) {
                float z = zac[mt];
#pragma unroll
                for (int i = 0; i < 8; ++i) {
                    float e = __builtin_amdgcn_exp2f(fmaf(fq[i], gj[mt], nM[mt]));
                    z += e;
                    bv[mt][kt][i] = f2bf(e);
                }
                zac[mt] = z;
            }
        }
        // prefetch next superstep's f (independent of MFMA cluster)
        {
            int nn = ((2 * p + 2 + ws) & 127) * 32;
            fc[0] = *(const float4*)(fl0 + nn + 8 * hi);
            fc[1] = *(const float4*)(fl0 + nn + 8 * hi + 4);
            fc[2] = *(const float4*)(fl0 + nn + 16 + 8 * hi);
            fc[3] = *(const float4*)(fl0 + nn + 16 + 8 * hi + 4);
        }
        // ---- MFMA cluster: 16 x mfma_f32_32x32x16_bf16 ----
        const char* cbuf = smem + (rs + ws) * 16384;
#pragma unroll
        for (int kt = 0; kt < 2; ++kt) {
            int lslot = (kt * 2 + hi) * 16;
#pragma unroll
            for (int ct = 0; ct < 4; ++ct) {
                s16x8 av = *(const s16x8*)(cbuf + rowoff[ct] + (lslot ^ rkey[ct]));
                acc[ct][0] = __builtin_amdgcn_mfma_f32_32x32x16_bf16(av, bv[0][kt], acc[ct][0], 0, 0, 0);
                acc[ct][1] = __builtin_amdgcn_mfma_f32_32x32x16_bf16(av, bv[1][kt], acc[ct][1], 0, 0, 0);
            }
        }
        rs += 2;  if (rs >= 6) rs -= 6;
        ssl += 2; if (ssl >= 6) ssl -= 6;
    }
    __syncthreads();   // full drain (incl. wrap stages) before overlays

    // ---- Z finalize: lane + partner (hi) hold complementary k-halves ----
    float zf[2];
#pragma unroll
    for (int mt = 0; mt < 2; ++mt) {
        float z = zac[mt];
        z += __shfl_xor(z, 32);
        zf[mt] = z;
    }
    {
        float* zb = (float*)(smem + ZBUF_OFF);
        if (l < 32) {
#pragma unroll
            for (int mt = 0; mt < 2; ++mt) zb[w * 64 + mt * 32 + l] = zf[mt];
        }
        // ---- acc merge across ws pairs: ws1 -> LDS (f32, 4 x 32KB), ws0 adds ----
        int p8 = wc * 2 + wm;
        float* mrg = (float*)(smem + p8 * 32768);
        if (ws == 1) {
#pragma unroll
            for (int ct = 0; ct < 4; ++ct)
#pragma unroll
                for (int mt = 0; mt < 2; ++mt) {
                    int fi = ct * 2 + mt;
#pragma unroll
                    for (int j = 0; j < 4; ++j) {
                        f32x4 v = {acc[ct][mt][4*j], acc[ct][mt][4*j+1],
                                   acc[ct][mt][4*j+2], acc[ct][mt][4*j+3]};
                        *(f32x4*)(mrg + ((fi * 4 + j) * 64 + l) * 4) = v;
                    }
                }
        }
        __syncthreads();
        if (ws == 0) {
#pragma unroll
            for (int ct = 0; ct < 4; ++ct)
#pragma unroll
                for (int mt = 0; mt < 2; ++mt) {
                    int fi = ct * 2 + mt;
#pragma unroll
                    for (int j = 0; j < 4; ++j) {
                        f32x4 o = *(const f32x4*)(mrg + ((fi * 4 + j) * 64 + l) * 4);
#pragma unroll
                        for (int i = 0; i < 4; ++i) acc[ct][mt][4*j+i] += o[i];
                    }
                }
        }
#pragma unroll
        for (int mt = 0; mt < 2; ++mt) zf[mt] += zb[(w ^ 1) * 64 + mt * 32 + col];
        __syncthreads();   // merge reads done before y_lds overwrites region
    }

    // ---- y_norm -> LDS (ws0): y_lds[m][c] bf16, 512B rows, XOR-swizzled ----
    // 32x32 C/D: col = l&31, row = (reg&3) + 8*(reg>>2) + 4*hi
    if (ws == 0) {
        float rzl[2] = {1.0f / zf[0], 1.0f / zf[1]};
#pragma unroll
        for (int ct = 0; ct < 4; ++ct)
#pragma unroll
            for (int mt = 0; mt < 2; ++mt) {
                int mloc = wm * 64 + mt * 32 + col;
                int key = (mloc & 7) << 4;
#pragma unroll
                for (int j = 0; j < 4; ++j) {
                    int cb = (wc * 256 + ct * 64 + 16 * j + 8 * hi) ^ key;
                    s16x4 v;
#pragma unroll
                    for (int i = 0; i < 4; ++i) v[i] = f2bf(acc[ct][mt][4*j+i] * rzl[mt]);
                    *(s16x4*)(smem + mloc * 512 + cb) = v;
                }
            }
    }
    __syncthreads();

    // ---- GEMM2: o[c_out][m] = wv[c_out][:] . y_norm[:][m], K=256 (8 waves, 16x16) ----
    int co0 = w * 32;
    f32x4 acc2[2][8];
#pragma unroll
    for (int j2 = 0; j2 < 2; ++j2)
#pragma unroll
        for (int jm2 = 0; jm2 < 8; ++jm2) acc2[j2][jm2] = (f32x4){0.f, 0.f, 0.f, 0.f};

#pragma unroll 2
    for (int ks = 0; ks < 8; ++ks) {
        s16x8 a2[2];
#pragma unroll
        for (int j2 = 0; j2 < 2; ++j2) {
            const float* wr = wv + (size_t)(co0 + j2 * 16 + cr) * CQ + ks * 32 + q * 8;
            float4 wa = ld4(wr);
            float4 wb = ld4(wr + 4);
            a2[j2][0] = f2bf(wa.x); a2[j2][1] = f2bf(wa.y);
            a2[j2][2] = f2bf(wa.z); a2[j2][3] = f2bf(wa.w);
            a2[j2][4] = f2bf(wb.x); a2[j2][5] = f2bf(wb.y);
            a2[j2][6] = f2bf(wb.z); a2[j2][7] = f2bf(wb.w);
        }
#pragma unroll
        for (int jm2 = 0; jm2 < 8; ++jm2) {
            int mloc = jm2 * 16 + cr;
            s16x8 b2 = *(const s16x8*)(smem + mloc * 512 + ((ks * 64 + q * 16) ^ ((mloc & 7) << 4)));
#pragma unroll
            for (int j2 = 0; j2 < 2; ++j2)
                acc2[j2][jm2] = __builtin_amdgcn_mfma_f32_16x16x32_bf16(a2[j2], b2, acc2[j2][jm2], 0, 0, 0);
        }
    }

    // ---- epilogue ----
    float gam = gamma[0];
    float omg = 1.f - gam;
    if (gam != 0.f) {
#pragma unroll
        for (int j2 = 0; j2 < 2; ++j2)
#pragma unroll
            for (int jm2 = 0; jm2 < 8; ++jm2)
#pragma unroll
                for (int r = 0; r < 4; ++r) {
                    int c_out = co0 + j2 * 16 + q * 4 + r;
                    size_t idx = ((size_t)b * CQ + c_out) * NQ + m0 + jm2 * 16 + cr;
                    __builtin_nontemporal_store(
                        fmaf(gam, x[idx], acc2[j2][jm2][r] * omg), out + idx);
                }
    } else {
#pragma unroll
        for (int j2 = 0; j2 < 2; ++j2)
#pragma unroll
            for (int jm2 = 0; jm2 < 8; ++jm2)
#pragma unroll
                for (int r = 0; r < 4; ++r) {
                    int c_out = co0 + j2 * 16 + q * 4 + r;
                    size_t idx = ((size_t)b * CQ + c_out) * NQ + m0 + jm2 * 16 + cr;
                    __builtin_nontemporal_store(acc2[j2][jm2][r] * omg, out + idx);
                }
    }
}

extern "C" void kernel_launch(void* const* d_in, const int* in_sizes, int n_in,
                              void* d_out, int out_size, void* d_ws, size_t ws_size,
                              hipStream_t stream) {
    const float* x     = (const float*)d_in[0];
    const float* wq    = (const float*)d_in[1];
    const float* wk    = (const float*)d_in[2];
    const float* wv    = (const float*)d_in[3];
    const float* gamma = (const float*)d_in[4];
    float* out = (float*)d_out;

    // ws (floats): fs[B*N] | g[B*N] | fmxu[8]+fmnu[8] (uint) | pad -> xbf (bf16) [B*C*N]
    float* ws  = (float*)d_ws;
    float* fs  = ws;
    float* g   = ws + BQ * NQ;
    uint* fmxu = (uint*)(ws + 2 * BQ * NQ);
    uint* fmnu = fmxu + 8;
    short* xbf = (short*)(ws + 2 * BQ * NQ + 64);

    hipMemsetAsync(fmxu, 0x00, 32, stream);   // lowest key
    hipMemsetAsync(fmnu, 0xFF, 32, stream);   // highest key
    hipLaunchKernelGGL(k_fg, dim3(NQ / 64, BQ), dim3(256), 0, stream,
                       x, wq, wk, fs, g, xbf, fmxu, fmnu);
    hipLaunchKernelGGL(k_attn, dim3(BQ * (NQ / MT)), dim3(512), 0, stream,
                       xbf, fs, g, fmxu, fmnu, wv, x, gamma, out);
}